// Round 4
// baseline (101.590 us; speedup 1.0000x reference)
//
#include <hip/hip_runtime.h>

// out[b, i, p] = (i == i2[p] || i == j2[p]) ? NRF[b,p] * 0.5f : 0.0f
// B=1024, N_ATOMS=64, NC2=2016. Pair p = i2*(i2-1)/2 + j2 (j2 < i2).
//
// Thread owns (b, p4, i-quarter): loads NRF[b, p4] ONCE, decodes the 4
// pair memberships once, then emits 16 nontemporal float4 stores (i-loop).
// Removes the per-store L2-hit load of the previous version (load:store
// ratio 1:1 -> 1:16) and refines grain (8064 blocks = 31.5/CU).
// Store coalescing: lanes = consecutive p4 -> contiguous 1 KB per wave.

typedef float f32x4 __attribute__((ext_vector_type(4)));

__device__ __forceinline__ int pair_row(int p) {
    float f = sqrtf(8.0f * (float)p + 1.0f);
    int i = (int)((1.0f + f) * 0.5f);
    while (i * (i - 1) / 2 > p) --i;
    while ((i + 1) * i / 2 <= p) ++i;
    return i;
}

__global__ __launch_bounds__(256) void transform_nrf_kernel(
    const float* __restrict__ nrf, float* __restrict__ out) {
    const int t  = blockIdx.x * 256 + threadIdx.x;   // 0 .. 2064383
    const int p4 = t % 504;
    const int r1 = t / 504;
    const int b  = r1 % 1024;
    const int iq = r1 / 1024;                        // 0..3
    const int p0 = p4 * 4;

    // Decode the two member atoms of each of this thread's 4 pairs.
    int ia[4], jb[4];
#pragma unroll
    for (int k = 0; k < 4; ++k) {
        const int p = p0 + k;
        const int r = pair_row(p);
        ia[k] = r;
        jb[k] = p - r * (r - 1) / 2;
    }

    const f32x4 v = ((const f32x4*)nrf)[b * 504 + p4];
    f32x4 val;
    val.x = v.x * 0.5f; val.y = v.y * 0.5f;
    val.z = v.z * 0.5f; val.w = v.w * 0.5f;

    f32x4* __restrict__ out4 = (f32x4*)out;
    const int i0   = iq * 16;
    const int base = (b * 64 + i0) * 504 + p4;

#pragma unroll
    for (int k = 0; k < 16; ++k) {
        const int i = i0 + k;
        f32x4 o;
        o.x = (i == ia[0] || i == jb[0]) ? val.x : 0.0f;
        o.y = (i == ia[1] || i == jb[1]) ? val.y : 0.0f;
        o.z = (i == ia[2] || i == jb[2]) ? val.z : 0.0f;
        o.w = (i == ia[3] || i == jb[3]) ? val.w : 0.0f;
        __builtin_nontemporal_store(o, &out4[base + k * 504]);
    }
}

extern "C" void kernel_launch(void* const* d_in, const int* in_sizes, int n_in,
                              void* d_out, int out_size, void* d_ws, size_t ws_size,
                              hipStream_t stream) {
    const float* nrf = (const float*)d_in[0];
    float* out       = (float*)d_out;
    // 8064 blocks * 256 threads = 2,064,384 threads = 1024 b * 504 p4 * 4 iq.
    transform_nrf_kernel<<<8064, 256, 0, stream>>>(nrf, out);
}

// Round 5
// 85.540 us; speedup vs baseline: 1.1876x; 1.1876x over previous
//
#include <hip/hip_runtime.h>

// out[b, i, p] = (i == i2[p] || i == j2[p]) ? NRF[b,p] * 0.5f : 0.0f
// B=1024, N_ATOMS=64, NC2=2016. Pair p = i2*(i2-1)/2 + j2 (j2 < i2).
//
// Fill-shaped linear sweep: flat output in float4 units (33,030,144).
// Wave w of block n writes 4 contiguous KB (4 stores x 64 lanes x 16 B),
// blocks ascend linearly -> HBM sees the same sequential burst pattern as
// the 7 TB/s fillBufferAligned. Membership decoded per float4 from flat
// index: one magic-div by 504, one sqrt for the quad's first pair-row,
// then incremental row fix-ups (i2 advances <=1 per consecutive p).

typedef float f32x4 __attribute__((ext_vector_type(4)));

__device__ __forceinline__ int pair_row(int p) {
    float f = sqrtf(8.0f * (float)p + 1.0f);
    int i = (int)((1.0f + f) * 0.5f);
    while (i * (i - 1) / 2 > p) --i;
    while ((i + 1) * i / 2 <= p) ++i;
    return i;
}

__global__ __launch_bounds__(256) void transform_nrf_kernel(
    const float* __restrict__ nrf, float* __restrict__ out) {
    const unsigned wid   = threadIdx.x >> 6;
    const unsigned lane  = threadIdx.x & 63u;
    const unsigned wbase = blockIdx.x * 1024u + wid * 256u;  // float4 units

    const f32x4* __restrict__ nrf4 = (const f32x4*)nrf;
    f32x4* __restrict__ out4       = (f32x4*)out;

#pragma unroll
    for (int jj = 0; jj < 4; ++jj) {
        const unsigned f   = wbase + jj * 64u + lane;  // flat float4 index
        const unsigned row = f / 504u;                 // b*64 + i (magic div)
        const unsigned p4  = f - row * 504u;
        const unsigned b   = row >> 6;
        const int      i   = (int)(row & 63u);
        const int      p0  = (int)(p4 * 4u);

        const f32x4 v = nrf4[b * 504u + p4];
        const float vv[4] = {v.x * 0.5f, v.y * 0.5f, v.z * 0.5f, v.w * 0.5f};

        int t = pair_row(p0);
        float oo[4];
#pragma unroll
        for (int c = 0; c < 4; ++c) {
            const int p = p0 + c;
            if (c > 0) t += (p >= ((t + 1) * t) / 2) ? 1 : 0;
            const int j2 = p - (t * (t - 1)) / 2;
            oo[c] = ((i == t) || (i == j2)) ? vv[c] : 0.0f;
        }

        f32x4 o = {oo[0], oo[1], oo[2], oo[3]};
        __builtin_nontemporal_store(o, &out4[f]);
    }
}

extern "C" void kernel_launch(void* const* d_in, const int* in_sizes, int n_in,
                              void* d_out, int out_size, void* d_ws, size_t ws_size,
                              hipStream_t stream) {
    const float* nrf = (const float*)d_in[0];
    float* out       = (float*)d_out;
    // 33,030,144 float4 total / (256 threads * 4 stores) = 32,256 blocks.
    transform_nrf_kernel<<<32256, 256, 0, stream>>>(nrf, out);
}